// Round 1
// baseline (18.454 us; speedup 1.0000x reference)
//
#include <hip/hip_runtime.h>
#include <hip/hip_bf16.h>
#include <math.h>

#define HDIM 1024
#define BATCH 8
#define SEQ 4096

// ws layout: [0..255] per-block partial sum|W|, [256..256+8191] dot[b*H+o]

__global__ __launch_bounds__(256) void k_dot(const float* __restrict__ hs,
                                             const float* __restrict__ W,
                                             float* __restrict__ partial,
                                             float* __restrict__ dot) {
    __shared__ float sx[BATCH * HDIM];   // 32 KB: sign of first token, 8 batches
    __shared__ float wabs[4];
    const int tid = threadIdx.x;

    // cooperative load of 8 first-token rows -> sign values in LDS
    #pragma unroll
    for (int i = 0; i < (BATCH * HDIM) / 256; ++i) {
        int idx = tid + i * 256;
        int b = idx >> 10, h = idx & (HDIM - 1);
        float v = hs[(size_t)b * (SEQ * HDIM) + h];
        sx[idx] = (v > 0.f) ? 1.f : ((v < 0.f) ? -1.f : 0.f);
    }
    __syncthreads();

    const int wave = tid >> 6, lane = tid & 63;
    const int o = blockIdx.x * 4 + wave;          // W row this wave owns
    const float* wrow = W + (size_t)o * HDIM;

    float acc[BATCH];
    #pragma unroll
    for (int b = 0; b < BATCH; ++b) acc[b] = 0.f;
    float aabs = 0.f;

    #pragma unroll
    for (int k = 0; k < HDIM / 64; ++k) {
        int h = lane + k * 64;                    // coalesced 256B/wave
        float wv = wrow[h];
        float s = (wv > 0.f) ? 1.f : ((wv < 0.f) ? -1.f : 0.f);
        aabs += fabsf(wv);
        #pragma unroll
        for (int b = 0; b < BATCH; ++b) acc[b] += s * sx[b * HDIM + h];
    }

    // wave-64 butterfly reduce
    #pragma unroll
    for (int off = 32; off >= 1; off >>= 1) {
        aabs += __shfl_down(aabs, off, 64);
        #pragma unroll
        for (int b = 0; b < BATCH; ++b) acc[b] += __shfl_down(acc[b], off, 64);
    }
    if (lane == 0) {
        #pragma unroll
        for (int b = 0; b < BATCH; ++b) dot[b * HDIM + o] = acc[b];
        wabs[wave] = aabs;
    }
    __syncthreads();
    if (tid == 0) partial[blockIdx.x] = wabs[0] + wabs[1] + wabs[2] + wabs[3];
}

__global__ __launch_bounds__(256) void k_fin(const float* __restrict__ partial,
                                             const float* __restrict__ dot,
                                             const float* __restrict__ bias,
                                             const float* __restrict__ alpha,
                                             float* __restrict__ out) {
    __shared__ float red[256];
    const int tid = threadIdx.x;
    red[tid] = partial[tid];
    __syncthreads();
    #pragma unroll
    for (int off = 128; off >= 1; off >>= 1) {
        if (tid < off) red[tid] += red[tid + off];
        __syncthreads();
    }
    float a = alpha[0];
    if (a < 1e-5f) a = 1e-5f;
    const float scale = a * red[0] * (1.0f / (1024.0f * 1024.0f));

    const int idx = blockIdx.x * 256 + tid;       // b*1024 + o
    const int b = idx >> 10, o = idx & (HDIM - 1);
    out[idx] = tanhf(scale * dot[b * HDIM + o] + bias[o]);
}

extern "C" void kernel_launch(void* const* d_in, const int* in_sizes, int n_in,
                              void* d_out, int out_size, void* d_ws, size_t ws_size,
                              hipStream_t stream) {
    const float* hs    = (const float*)d_in[0];
    const float* W     = (const float*)d_in[1];
    const float* bias  = (const float*)d_in[2];
    const float* alpha = (const float*)d_in[3];
    float* out = (float*)d_out;

    float* partial = (float*)d_ws;          // 256 floats
    float* dot     = partial + 256;         // 8192 floats

    k_dot<<<HDIM / 4, 256, 0, stream>>>(hs, W, partial, dot);
    k_fin<<<(BATCH * HDIM) / 256, 256, 0, stream>>>(partial, dot, bias, alpha, out);
}

// Round 2
// 13.485 us; speedup vs baseline: 1.3685x; 1.3685x over previous
//
#include <hip/hip_runtime.h>
#include <hip/hip_bf16.h>
#include <math.h>

#define HDIM 1024
#define BATCH 8
#define SEQ 4096

// d_ws layout (u64 units):
//   [0, 16K)        wsgn_t[16][1024]  bit l of word (w=k*4+j, o): W[o][k*256+l*4+j] < 0
//   [16K, 32K)      wnz_t [16][1024]  same mapping, value != 0
//   [32K, 32K+128)  xsgn[8][16]
//   [32K+128, +256) xnz [8][16]
//   then (as float*) wabs[1024]  per-row sum|W|
#define U64_WSGN 0
#define U64_WNZ  (16 * 1024)
#define U64_XSGN (32 * 1024)
#define U64_XNZ  (32 * 1024 + 128)
#define U64_TOT  (32 * 1024 + 256)

__global__ __launch_bounds__(256) void k_masks(const float* __restrict__ hs,
                                               const float* __restrict__ W,
                                               unsigned long long* __restrict__ ws64,
                                               float* __restrict__ wabs) {
    const int tid = threadIdx.x;
    const int wave = tid >> 6, lane = tid & 63;

    const bool isW = blockIdx.x < 256;
    int o = 0, b = 0;
    const float* row;
    if (isW) { o = blockIdx.x * 4 + wave; row = W + (size_t)o * HDIM; }
    else     { b = (blockIdx.x - 256) * 4 + wave; row = hs + (size_t)b * SEQ * HDIM; }

    float aabs = 0.f;
    #pragma unroll
    for (int k = 0; k < 4; ++k) {
        float4 v = *reinterpret_cast<const float4*>(row + k * 256 + lane * 4);
        float e0 = v.x, e1 = v.y, e2 = v.z, e3 = v.w;
        const float ee[4] = {e0, e1, e2, e3};
        #pragma unroll
        for (int j = 0; j < 4; ++j) {
            unsigned long long sg = __ballot(ee[j] < 0.f);
            unsigned long long nz = __ballot(ee[j] != 0.f);
            const int w = k * 4 + j;
            if (lane == 0) {
                if (isW) {
                    ws64[U64_WSGN + w * 1024 + o] = sg;
                    ws64[U64_WNZ  + w * 1024 + o] = nz;
                } else {
                    ws64[U64_XSGN + b * 16 + w] = sg;
                    ws64[U64_XNZ  + b * 16 + w] = nz;
                }
            }
            aabs += fabsf(ee[j]);
        }
    }
    if (isW) {
        #pragma unroll
        for (int off = 32; off >= 1; off >>= 1) aabs += __shfl_down(aabs, off, 64);
        if (lane == 0) wabs[o] = aabs;
    }
}

__global__ __launch_bounds__(256) void k_out(const unsigned long long* __restrict__ ws64,
                                             const float* __restrict__ wabs,
                                             const float* __restrict__ bias,
                                             const float* __restrict__ alpha,
                                             float* __restrict__ out) {
    __shared__ float red[256];
    __shared__ unsigned long long lx[32];  // [0..15]=xsgn, [16..31]=xnz for this b
    const int tid = threadIdx.x;
    const int b = blockIdx.x >> 2;
    const int o = (blockIdx.x & 3) * 256 + tid;

    if (tid < 16)       lx[tid] = ws64[U64_XSGN + b * 16 + tid];
    else if (tid < 32)  lx[tid] = ws64[U64_XNZ + b * 16 + (tid - 16)];

    red[tid] = wabs[tid] + wabs[tid + 256] + wabs[tid + 512] + wabs[tid + 768];
    __syncthreads();
    #pragma unroll
    for (int off = 128; off >= 1; off >>= 1) {
        if (tid < off) red[tid] += red[tid + off];
        __syncthreads();
    }

    int n = 0, d = 0;
    #pragma unroll
    for (int w = 0; w < 16; ++w) {
        unsigned long long wsg = ws64[U64_WSGN + w * 1024 + o];
        unsigned long long wnz = ws64[U64_WNZ  + w * 1024 + o];
        unsigned long long u = wnz & lx[16 + w];
        unsigned long long m = (wsg ^ lx[w]) & u;
        n += __popcll(u);
        d += __popcll(m);
    }

    float a = alpha[0];
    if (a < 1e-5f) a = 1e-5f;
    const float scale = a * red[0] * (1.0f / 1048576.0f);
    out[b * HDIM + o] = tanhf(scale * (float)(n - 2 * d) + bias[o]);
}

extern "C" void kernel_launch(void* const* d_in, const int* in_sizes, int n_in,
                              void* d_out, int out_size, void* d_ws, size_t ws_size,
                              hipStream_t stream) {
    const float* hs    = (const float*)d_in[0];
    const float* W     = (const float*)d_in[1];
    const float* bias  = (const float*)d_in[2];
    const float* alpha = (const float*)d_in[3];
    float* out = (float*)d_out;

    unsigned long long* ws64 = (unsigned long long*)d_ws;
    float* wabs = (float*)(ws64 + U64_TOT);

    k_masks<<<258, 256, 0, stream>>>(hs, W, ws64, wabs);
    k_out<<<(BATCH * HDIM) / 256, 256, 0, stream>>>(ws64, wabs, bias, alpha, out);
}